// Round 10
// baseline (96.288 us; speedup 1.0000x reference)
//
#include <hip/hip_runtime.h>
#include <stdint.h>

typedef unsigned short u16;
typedef unsigned int u32;
typedef unsigned long long u64;

typedef __bf16 bf16x8 __attribute__((ext_vector_type(8)));
typedef float f32x4 __attribute__((ext_vector_type(4)));
typedef u16 u16x2 __attribute__((ext_vector_type(2)));

#define NQ 512
#define NC 16
#define NH 128
#define NB 2048
#define QE_KEYS (513*128)          // 65664 u16 keys
#define WT_OFF  QE_KEYS            // bf16 W copy
#define GW_ELEMS (128*128)
#define A_OFF (WT_OFF + GW_ELEMS)  // a_norm bf16, padded 16x32 (K 16->32 zeros)
#define LSEG 1088                  // per-wave list segment (16*64=1024 + pad), u16
#define ESEG 2304                  // per-wave sE segment (16*136=2176 + pad), u16
#define ESTRIDE 136

static __device__ __forceinline__ u16 f2bf_rne(float f){
  u32 u = __float_as_uint(f);
  u += 0x7fffu + ((u>>16)&1u);
  return (u16)(u>>16);
}
static __device__ __forceinline__ u32 pack_rne(float lo, float hi){
  return (u32)f2bf_rne(lo) | ((u32)f2bf_rne(hi)<<16);
}
// monotone key: unsigned compare on keys == float compare on bf16 values
static __device__ __forceinline__ u16 key_of(float f){
  u16 b = f2bf_rne(f);
  return (b & 0x8000u) ? (u16)~b : (u16)(b | 0x8000u);
}
// packed u16 max (v_pk_max_u16)
static __device__ __forceinline__ u32 pkmax(u32 a, u32 b){
  union { u32 s; u16x2 v; } A, B, R;
  A.s = a; B.s = b;
  R.v = __builtin_elementwise_max(A.v, B.v);
  return R.s;
}
// packed unkey: per half, (k&0x8000) ? k^0x8000 : ~k
static __device__ __forceinline__ u32 unkey_pk(u32 x){
  u32 sel = x & 0x80008000u;
  sel = sel | (sel - (sel >> 15));        // 0xffff per half with top bit set
  return (sel & (x ^ 0x80008000u)) | (~sel & ~x);
}

union Frag { u32 u[4]; uint4 u4; bf16x8 f; };

// ---- prepass: keys, bf16 W, and precomputed a_norm A-fragment table ----
__global__ void prepass_kernel(const float* __restrict__ qe,
                               const float* __restrict__ gw,
                               const float* __restrict__ adj,
                               u16* __restrict__ ws)
{
  if (blockIdx.x == 0) {            // a_norm = adj * dinv_i * dinv_j, padded 16x32
    __shared__ float sD[16];
    int t = threadIdx.x;
    if (t < 16) {
      float s = 0.f;
      for (int i = 0; i < 16; ++i) s += adj[i*16 + t];
      sD[t] = (s > 0.f) ? (1.0f / sqrtf(s)) : 0.f;
    }
    __syncthreads();
    int i = t >> 4, jp = (t & 15) * 2;   // row i, cols jp, jp+1 of 32
    float lo = (jp   < 16) ? adj[i*16 + jp]   * sD[i] * sD[jp]   : 0.f;
    float hi = (jp+1 < 16) ? adj[i*16 + jp+1] * sD[i] * sD[jp+1] : 0.f;
    ((u32*)(ws + A_OFF))[t] = pack_rne(lo, hi);
    return;
  }
  int idx = (blockIdx.x - 1) * 256 + threadIdx.x;
  if (idx < QE_KEYS/8) {                       // key table
    int i8 = idx * 8;
    uint4 o;
    if (i8 >= 512*NH) {                        // row 512: key of +0.0
      o.x = 0x80008000u; o.y = 0x80008000u; o.z = 0x80008000u; o.w = 0x80008000u;
    } else {
      const float4* p = (const float4*)(qe + i8);
      float4 a = p[0], b = p[1];
      o.x = (u32)key_of(a.x) | ((u32)key_of(a.y)<<16);
      o.y = (u32)key_of(a.z) | ((u32)key_of(a.w)<<16);
      o.z = (u32)key_of(b.x) | ((u32)key_of(b.y)<<16);
      o.w = (u32)key_of(b.z) | ((u32)key_of(b.w)<<16);
    }
    *(uint4*)(ws + i8) = o;
  } else if (idx < QE_KEYS/8 + GW_ELEMS/8) {   // W -> bf16
    int j8 = (idx - QE_KEYS/8) * 8;
    const float4* p = (const float4*)(gw + j8);
    float4 a = p[0], b = p[1];
    uint4 o;
    o.x = pack_rne(a.x, a.y); o.y = pack_rne(a.z, a.w);
    o.z = pack_rne(b.x, b.y); o.w = pack_rne(b.z, b.w);
    *(uint4*)(ws + WT_OFF + j8) = o;
  }
}

// One wave == one item. NO __syncthreads: all LDS is wave-private.
__global__ __launch_bounds__(256, 4)
void core_snapshot_kernel(const int* __restrict__ la,
                          const u16* __restrict__ ws,
                          const float* __restrict__ gb,
                          float* __restrict__ outp)
{
  __shared__ __align__(16) u16 sListAll[4*LSEG];
  __shared__ __align__(16) u16 sEAll[4*ESEG];

  const int tid  = threadIdx.x;
  const int lane = tid & 63;
  const int wv   = tid >> 6;
  const int m    = lane & 15;
  const int quad = lane >> 4;
  const int half = lane >> 5;      // 0/1: row parity within a gather pair
  const int dimo = lane & 31;      // dword-pair: dims 4*dimo .. 4*dimo+3
  const int sh   = half * 16;      // bfe shift for slot extraction
  const int item = blockIdx.x*4 + wv;
  u16* sList = sListAll + wv*LSEG;
  u16* sE    = sEAll    + wv*ESEG;
  const u16* qt = ws;
  const u16* wt = ws + WT_OFF;

  // prefill private list with 512 (pads gather the key-0 row == reference pad semantics)
  {
    uint4 f = make_uint4(0x02000200u,0x02000200u,0x02000200u,0x02000200u);
    *(uint4*)&sList[lane*16]     = f;
    *(uint4*)&sList[lane*16 + 8] = f;
  }

  // ---- phase 1: 8 chunks, in-register per-core running counts, no barriers ----
  int av[8];
  #pragma unroll
  for (int ch = 0; ch < 8; ++ch) av[ch] = la[item*NQ + ch*64 + lane];
  const u64 lmask = (1ull << lane) - 1ull;
  u32 runbase = 0;     // lane c (<16) holds running count for core c
  #pragma unroll
  for (int ch = 0; ch < 8; ++ch) {
    u32 cnt = 0, intra = 0;
    #pragma unroll
    for (int c = 0; c < 16; ++c) {
      u64 mk = __ballot(av[ch] == c);
      if (lane == c)    cnt   = (u32)__popcll(mk);
      if (av[ch] == c)  intra = (u32)__popcll(mk & lmask);
    }
    u32 base = (u32)__shfl((int)runbase, av[ch]);   // pre-chunk base for my core
    u32 rank = base + intra;
    if (rank < 64) sList[av[ch]*64 + rank] = (u16)(ch*64 + lane);  // natural order
    runbase += cnt;
  }
  const u32 cntv = runbase;   // lane c: total count of core c

  // ---- phase 2: 2-rows-per-instruction gather, dwordx2/lane, exact-ish coverage ----
  // lanes 0..31 cover row 2k, lanes 32..63 row 2k+1; each half = one full 256B row.
  const u16* qrow = qt + dimo*4;    // + idx*NH
  #define GBATCH(E0, N) { \
    u32 wd[N]; uint2 T[N]; \
    _Pragma("unroll") for (int k2 = 0; k2 < N/4; ++k2) { \
      uint4 W = *(const uint4*)&sList[c*64 + (E0) + k2*8]; \
      wd[k2*4+0]=W.x; wd[k2*4+1]=W.y; wd[k2*4+2]=W.z; wd[k2*4+3]=W.w; } \
    _Pragma("unroll") for (int k = 0; k < N; ++k) { \
      int id = (int)((wd[k] >> sh) & 0xffffu); \
      T[k] = *(const uint2*)(qrow + id*NH); } \
    _Pragma("unroll") for (int k = 0; k < N; ++k) { \
      ax = pkmax(ax, T[k].x); ay = pkmax(ay, T[k].y); } }

  for (int c = 0; c < 16; ++c) {
    int cmin = __builtin_amdgcn_readlane((int)cntv, c);
    cmin = (cmin > 64) ? 64 : cmin;
    u32 ax = 0, ay = 0;                 // key 0 < all value keys
    GBATCH(0, 8)                        // rows 0..15 (always)
    GBATCH(16, 8)                       // rows 16..31 (P(cnt<=16) ~ 0.2%: pads are cheap)
    if (cmin > 32) GBATCH(32, 4)        // rows 32..39
    if (cmin > 40) GBATCH(40, 4)        // rows 40..47
    if (cmin > 48) GBATCH(48, 4)        // rows 48..55
    if (cmin > 56) GBATCH(56, 4)        // rows 56..63
    // combine the two row-parities
    ax = pkmax(ax, (u32)__shfl_xor((int)ax, 32));
    ay = pkmax(ay, (u32)__shfl_xor((int)ay, 32));
    if (cmin < 64) {                    // relu via key(+0) for under-full cores
      ax = pkmax(ax, 0x80008000u);
      ay = pkmax(ay, 0x80008000u);
    }
    u32 ex = unkey_pk(ax), ey = unkey_pk(ay);
    if (half == 0)                      // dims 4*dimo..4*dimo+3, natural order
      *(uint2*)&sE[c*ESTRIDE + dimo*4] = make_uint2(ex, ey);
  }
  #undef GBATCH

  // ---- phases 3+4 fused per o-tile; H transposed via cross-quad shuffles ----
  bf16x8 af[4];   // E A-fragments (same-wave LDS RAW -> lgkm wait, no barrier)
  #pragma unroll
  for (int ks = 0; ks < 4; ++ks)
    af[ks] = *(const bf16x8*)&sE[m*ESTRIDE + ks*32 + quad*8];
  Frag anf;       // a_norm A-fragment (precomputed, padded K zeros)
  anf.u4 = *(const uint4*)(ws + A_OFF + m*32 + quad*8);

  #pragma unroll
  for (int t = 0; t < 8; ++t) {
    // H tile: C-layout acc[r] = H[core=quad*4+r][o=t*16+m]
    f32x4 acc = {0.f, 0.f, 0.f, 0.f};
    #pragma unroll
    for (int ks = 0; ks < 4; ++ks) {
      bf16x8 bfr = *(const bf16x8*)(wt + (t*16 + m)*NH + ks*32 + quad*8);
      acc = __builtin_amdgcn_mfma_f32_16x16x32_bf16(af[ks], bfr, acc, 0, 0, 0);
    }
    // B-frag for out-GEMM: lane(m,q) j-th elem = H[core=q*8+j][o=t*16+m], q<2
    float d16[4], d32[4], lo[4], hi[4];
    #pragma unroll
    for (int r = 0; r < 4; ++r) {
      d16[r] = __shfl_down(acc[r], 16);
      d32[r] = __shfl_down(acc[r], 32);
    }
    #pragma unroll
    for (int r = 0; r < 4; ++r) {
      lo[r] = (quad == 0) ? acc[r] : d16[r];
      hi[r] = (quad == 0) ? d16[r] : d32[r];
    }
    Frag hb;
    hb.u[0] = pack_rne(lo[0], lo[1]); hb.u[1] = pack_rne(lo[2], lo[3]);
    hb.u[2] = pack_rne(hi[0], hi[1]); hb.u[3] = pack_rne(hi[2], hi[3]);
    if (quad >= 2) { hb.u[0]=0; hb.u[1]=0; hb.u[2]=0; hb.u[3]=0; }  // K-pad
    float biasv = gb[t*16 + m];
    f32x4 o4 = {biasv, biasv, biasv, biasv};
    o4 = __builtin_amdgcn_mfma_f32_16x16x32_bf16(anf.f, hb.f, o4, 0, 0, 0);
    // C/D: col=lane&15 (o in tile), row=quad*4+reg (core)
    float* op = outp + item*(NC*NH) + t*16 + m;
    #pragma unroll
    for (int r = 0; r < 4; ++r) op[(quad*4 + r)*NH] = o4[r];
  }
}

extern "C" void kernel_launch(void* const* d_in, const int* in_sizes, int n_in,
                              void* d_out, int out_size, void* d_ws, size_t ws_size,
                              hipStream_t stream) {
  const int*   la  = (const int*)d_in[0];    // (2048, 512) int32
  const float* adj = (const float*)d_in[1];  // (16,16) fp32
  const float* qe  = (const float*)d_in[2];  // (513,128) fp32
  const float* gw  = (const float*)d_in[3];  // (128,128) fp32
  const float* gb  = (const float*)d_in[4];  // (128,) fp32
  float* outp = (float*)d_out;               // (2048,16,128) fp32
  u16* ws = (u16*)d_ws;                      // keys + bf16 W + a_norm frag

  int pre_blocks = 1 + (QE_KEYS/8 + GW_ELEMS/8 + 255)/256;   // 42
  prepass_kernel<<<pre_blocks, 256, 0, stream>>>(qe, gw, adj, ws);
  core_snapshot_kernel<<<NB/4, 256, 0, stream>>>(la, ws, gb, outp);
}

// Round 11
// 92.842 us; speedup vs baseline: 1.0371x; 1.0371x over previous
//
#include <hip/hip_runtime.h>
#include <stdint.h>

typedef unsigned short u16;
typedef unsigned int u32;
typedef unsigned long long u64;

typedef __bf16 bf16x8 __attribute__((ext_vector_type(8)));
typedef float f32x4 __attribute__((ext_vector_type(4)));
typedef u16 u16x8 __attribute__((ext_vector_type(8)));

#define NQ 512
#define NC 16
#define NH 128
#define NB 2048
#define QE_KEYS (513*128)          // 65664 u16 keys
#define WT_OFF  QE_KEYS            // bf16 W copy
#define GW_ELEMS (128*128)
#define A_OFF (WT_OFF + GW_ELEMS)  // a_norm bf16, padded 16x32 (K 16->32 zeros)
#define LSEG 1088                  // per-wave list segment (16*64=1024 + pad), u16
#define ESEG 2304                  // per-wave sE segment (16*136=2176 + pad), u16
#define ESTRIDE 136

static __device__ __forceinline__ u16 f2bf_rne(float f){
  u32 u = __float_as_uint(f);
  u += 0x7fffu + ((u>>16)&1u);
  return (u16)(u>>16);
}
static __device__ __forceinline__ u32 pack_rne(float lo, float hi){
  return (u32)f2bf_rne(lo) | ((u32)f2bf_rne(hi)<<16);
}
// monotone key: unsigned compare on keys == float compare on bf16 values
static __device__ __forceinline__ u16 key_of(float f){
  u16 b = f2bf_rne(f);
  return (b & 0x8000u) ? (u16)~b : (u16)(b | 0x8000u);
}
static __device__ __forceinline__ u16 unkey(u16 k){
  return (k & 0x8000u) ? (u16)(k ^ 0x8000u) : (u16)~k;
}

union Frag { u32 u[4]; uint4 u4; bf16x8 f; };
union U8   { u16x8 v; int w[4]; uint4 u4; u16 h[8]; };

// ---- prepass: keys, bf16 W, and precomputed a_norm A-fragment table ----
__global__ void prepass_kernel(const float* __restrict__ qe,
                               const float* __restrict__ gw,
                               const float* __restrict__ adj,
                               u16* __restrict__ ws)
{
  if (blockIdx.x == 0) {            // a_norm = adj * dinv_i * dinv_j, padded 16x32
    __shared__ float sD[16];
    int t = threadIdx.x;
    if (t < 16) {
      float s = 0.f;
      for (int i = 0; i < 16; ++i) s += adj[i*16 + t];
      sD[t] = (s > 0.f) ? (1.0f / sqrtf(s)) : 0.f;
    }
    __syncthreads();
    int i = t >> 4, jp = (t & 15) * 2;   // row i, cols jp, jp+1 of 32
    float lo = (jp   < 16) ? adj[i*16 + jp]   * sD[i] * sD[jp]   : 0.f;
    float hi = (jp+1 < 16) ? adj[i*16 + jp+1] * sD[i] * sD[jp+1] : 0.f;
    ((u32*)(ws + A_OFF))[t] = pack_rne(lo, hi);
    return;
  }
  int idx = (blockIdx.x - 1) * 256 + threadIdx.x;
  if (idx < QE_KEYS/8) {                       // key table
    int i8 = idx * 8;
    uint4 o;
    if (i8 >= 512*NH) {                        // row 512: key of +0.0
      o.x = 0x80008000u; o.y = 0x80008000u; o.z = 0x80008000u; o.w = 0x80008000u;
    } else {
      const float4* p = (const float4*)(qe + i8);
      float4 a = p[0], b = p[1];
      o.x = (u32)key_of(a.x) | ((u32)key_of(a.y)<<16);
      o.y = (u32)key_of(a.z) | ((u32)key_of(a.w)<<16);
      o.z = (u32)key_of(b.x) | ((u32)key_of(b.y)<<16);
      o.w = (u32)key_of(b.z) | ((u32)key_of(b.w)<<16);
    }
    *(uint4*)(ws + i8) = o;
  } else if (idx < QE_KEYS/8 + GW_ELEMS/8) {   // W -> bf16
    int j8 = (idx - QE_KEYS/8) * 8;
    const float4* p = (const float4*)(gw + j8);
    float4 a = p[0], b = p[1];
    uint4 o;
    o.x = pack_rne(a.x, a.y); o.y = pack_rne(a.z, a.w);
    o.z = pack_rne(b.x, b.y); o.w = pack_rne(b.z, b.w);
    *(uint4*)(ws + WT_OFF + j8) = o;
  }
}

static __device__ __forceinline__ void wave_reduce_max(U8& A){
  U8 B;
  #pragma unroll
  for (int j = 0; j < 4; ++j) B.w[j] = __shfl_xor(A.w[j], 16);
  A.v = __builtin_elementwise_max(A.v, B.v);
  #pragma unroll
  for (int j = 0; j < 4; ++j) B.w[j] = __shfl_xor(A.w[j], 32);
  A.v = __builtin_elementwise_max(A.v, B.v);
}

// One wave == one item. NO __syncthreads anywhere: all LDS is wave-private.
__global__ __launch_bounds__(256, 4)
void core_snapshot_kernel(const int* __restrict__ la,
                          const u16* __restrict__ ws,
                          const float* __restrict__ gb,
                          float* __restrict__ outp)
{
  __shared__ __align__(16) u16 sListAll[4*LSEG];
  __shared__ __align__(16) u16 sEAll[4*ESEG];

  const int tid  = threadIdx.x;
  const int lane = tid & 63;
  const int wv   = tid >> 6;
  const int m    = lane & 15;
  const int quad = lane >> 4;
  const int item = blockIdx.x*4 + wv;
  u16* sList = sListAll + wv*LSEG;
  u16* sE    = sEAll    + wv*ESEG;
  const u16* qt = ws;
  const u16* wt = ws + WT_OFF;

  // prefill private list with 512 (pads gather the key-0 row == reference pad semantics)
  {
    uint4 f = make_uint4(0x02000200u,0x02000200u,0x02000200u,0x02000200u);
    *(uint4*)&sList[lane*16]     = f;
    *(uint4*)&sList[lane*16 + 8] = f;
  }

  // ---- phase 1: 8 chunks, in-register per-core running counts, no barriers ----
  int av[8];
  #pragma unroll
  for (int ch = 0; ch < 8; ++ch) av[ch] = la[item*NQ + ch*64 + lane];
  const u64 lmask = (1ull << lane) - 1ull;
  u32 runbase = 0;     // lane c (<16) holds running count for core c
  #pragma unroll
  for (int ch = 0; ch < 8; ++ch) {
    u32 cnt = 0, intra = 0;
    #pragma unroll
    for (int c = 0; c < 16; ++c) {
      u64 mk = __ballot(av[ch] == c);
      if (lane == c)    cnt   = (u32)__popcll(mk);
      if (av[ch] == c)  intra = (u32)__popcll(mk & lmask);
    }
    u32 base = (u32)__shfl((int)runbase, av[ch]);   // pre-chunk base for my core
    u32 rank = base + intra;
    // transposed: quad q's 16 entries [q*16+k] hold ranks q+4k (contiguous 32 B)
    if (rank < 64) sList[av[ch]*64 + (rank&3)*16 + (rank>>2)] = (u16)(ch*64 + lane);
    runbase += cnt;
  }
  const u32 cntv = runbase;   // lane c: total count of core c

  // ---- phase 2: per-core gather from L2, 8-deep batches, packed-u16 max ----
  const u16* qb = qt + m*8;   // this lane's 8-dim chunk
  for (int c = 0; c < 16; ++c) {
    int cnt = __shfl((int)cntv, c);
    U8 S0, S1;
    S0.u4 = *(const uint4*)&sList[c*64 + quad*16];      // ranks quad+4k, k=0..7  (<32)
    S1.u4 = *(const uint4*)&sList[c*64 + quad*16 + 8];  // k=8..15 (ranks 32..63)
    U8 A; A.v = (u16x8)0;                               // key 0 < all value keys
    {
      U8 T[8];
      #pragma unroll
      for (int k = 0; k < 8; ++k) T[k].u4 = *(const uint4*)(qb + (int)S0.h[k]*NH);
      #pragma unroll
      for (int k = 0; k < 8; ++k) A.v = __builtin_elementwise_max(A.v, T[k].v);
    }
    if (cnt > 32) {   // wave-uniform branch; pads (row 512) give key(+0)
      U8 T[8];
      #pragma unroll
      for (int k = 0; k < 8; ++k) T[k].u4 = *(const uint4*)(qb + (int)S1.h[k]*NH);
      #pragma unroll
      for (int k = 0; k < 8; ++k) A.v = __builtin_elementwise_max(A.v, T[k].v);
    }
    wave_reduce_max(A);
    if (cnt < 64) {   // relu via key(+0) (redundant with pads, kept for robustness)
      U8 Z; Z.v = (u16x8)(u16)0x8000u;
      A.v = __builtin_elementwise_max(A.v, Z.v);
    }
    if (quad == 0) {
      uint4 e;
      e.x = (u32)unkey(A.h[0]) | ((u32)unkey(A.h[1])<<16);
      e.y = (u32)unkey(A.h[2]) | ((u32)unkey(A.h[3])<<16);
      e.z = (u32)unkey(A.h[4]) | ((u32)unkey(A.h[5])<<16);
      e.w = (u32)unkey(A.h[6]) | ((u32)unkey(A.h[7])<<16);
      *(uint4*)&sE[c*ESTRIDE + m*8] = e;
    }
  }

  // ---- phases 3+4 fused per o-tile; H transposed via cross-quad shuffles ----
  bf16x8 af[4];   // E A-fragments (same-wave LDS RAW -> lgkm wait, no barrier)
  #pragma unroll
  for (int ks = 0; ks < 4; ++ks)
    af[ks] = *(const bf16x8*)&sE[m*ESTRIDE + ks*32 + quad*8];
  Frag anf;       // a_norm A-fragment (precomputed, padded K zeros)
  anf.u4 = *(const uint4*)(ws + A_OFF + m*32 + quad*8);

  #pragma unroll
  for (int t = 0; t < 8; ++t) {
    // H tile: C-layout acc[r] = H[core=quad*4+r][o=t*16+m]
    f32x4 acc = {0.f, 0.f, 0.f, 0.f};
    #pragma unroll
    for (int ks = 0; ks < 4; ++ks) {
      bf16x8 bfr = *(const bf16x8*)(wt + (t*16 + m)*NH + ks*32 + quad*8);
      acc = __builtin_amdgcn_mfma_f32_16x16x32_bf16(af[ks], bfr, acc, 0, 0, 0);
    }
    // B-frag for out-GEMM: lane(m,q) j-th elem = H[core=q*8+j][o=t*16+m], q<2
    float d16[4], d32[4], lo[4], hi[4];
    #pragma unroll
    for (int r = 0; r < 4; ++r) {
      d16[r] = __shfl_down(acc[r], 16);
      d32[r] = __shfl_down(acc[r], 32);
    }
    #pragma unroll
    for (int r = 0; r < 4; ++r) {
      lo[r] = (quad == 0) ? acc[r] : d16[r];
      hi[r] = (quad == 0) ? d16[r] : d32[r];
    }
    Frag hb;
    hb.u[0] = pack_rne(lo[0], lo[1]); hb.u[1] = pack_rne(lo[2], lo[3]);
    hb.u[2] = pack_rne(hi[0], hi[1]); hb.u[3] = pack_rne(hi[2], hi[3]);
    if (quad >= 2) { hb.u[0]=0; hb.u[1]=0; hb.u[2]=0; hb.u[3]=0; }  // K-pad: keep 0*0
    float biasv = gb[t*16 + m];
    f32x4 o4 = {biasv, biasv, biasv, biasv};
    o4 = __builtin_amdgcn_mfma_f32_16x16x32_bf16(anf.f, hb.f, o4, 0, 0, 0);
    // C/D: col=lane&15 (o in tile), row=quad*4+reg (core)
    float* op = outp + item*(NC*NH) + t*16 + m;
    #pragma unroll
    for (int r = 0; r < 4; ++r) op[(quad*4 + r)*NH] = o4[r];
  }
}

extern "C" void kernel_launch(void* const* d_in, const int* in_sizes, int n_in,
                              void* d_out, int out_size, void* d_ws, size_t ws_size,
                              hipStream_t stream) {
  const int*   la  = (const int*)d_in[0];    // (2048, 512) int32
  const float* adj = (const float*)d_in[1];  // (16,16) fp32
  const float* qe  = (const float*)d_in[2];  // (513,128) fp32
  const float* gw  = (const float*)d_in[3];  // (128,128) fp32
  const float* gb  = (const float*)d_in[4];  // (128,) fp32
  float* outp = (float*)d_out;               // (2048,16,128) fp32
  u16* ws = (u16*)d_ws;                      // keys + bf16 W + a_norm frag

  int pre_blocks = 1 + (QE_KEYS/8 + GW_ELEMS/8 + 255)/256;   // 42
  prepass_kernel<<<pre_blocks, 256, 0, stream>>>(qe, gw, adj, ws);
  core_snapshot_kernel<<<NB/4, 256, 0, stream>>>(la, ws, gb, outp);
}